// Round 8
// baseline (172.554 us; speedup 1.0000x reference)
//
#include <hip/hip_runtime.h>
#include <cfloat>
#include <math.h>

#define E 16
#define DFULL 1024
#define DM 128
#define S 64
#define P 2048
#define B 8
#define C 256
#define W 3
#define H 16
#define RQ 16   /* rows per k_p1 block chunk */
#define NCH 16  /* row chunks per (e,b) for k_p1 / kmx planes */
#define RQ2 16  /* rows per k_p2v block chunk */
#define NCH2 16 /* row chunks per (e,b) for k_p2v */
#define LOG2E 1.4426950408889634f
#define WST 272 /* s_w stride in u16: 16B-aligned rows */
#define SFT 68  /* s_f stride in floats: 16B-aligned rows, odd dword-quad */

typedef __attribute__((ext_vector_type(8))) short short8;
typedef __attribute__((ext_vector_type(4))) short short4v;
typedef __attribute__((ext_vector_type(4))) float f32x4;
#define MFMA_BF16(a, b, c) __builtin_amdgcn_mfma_f32_16x16x32_bf16((a), (b), (c), 0, 0, 0)

#if defined(__HIP_DEVICE_COMPILE__) && __has_builtin(__builtin_amdgcn_exp2f)
#define EXP2(x) __builtin_amdgcn_exp2f(x)
#else
#define EXP2(x) exp2f(x)
#endif

struct RoutesArg { int nb[E][W]; };

// ---------------- host: replicate _expert_routes() exactly ----------------
static void compute_routes(int r[E][W]) {
  float coords[E];
  for (int i = 0; i < E; ++i) {
    double x = (double)i / (double)(E - 1);
    if (x < 1e-06) x = 1e-06;
    if (x > 1.0 - 1e-06) x = 1.0 - 1e-06;
    double val = 0.0, factor = 0.5;
    for (int k = 0; k < 8; ++k) {
      x *= 3.0;
      int d = (int)x;
      x -= (double)d;
      if (d == 2) val += factor;
      factor *= 0.5;
    }
    coords[i] = (float)val;
  }
  for (int e = 0; e < E; ++e) {
    float de[E];
    for (int i = 0; i < E; ++i) de[i] = fabsf(coords[i] - coords[e]);
    bool used[E] = {false};
    for (int w = 0; w < W; ++w) {
      int best = -1; float bd = FLT_MAX;
      for (int i = 0; i < E; ++i)
        if (!used[i] && de[i] < bd) { bd = de[i]; best = i; }  // strict < = stable
      used[best] = true;
      r[e][w] = best;
    }
  }
}

__device__ __forceinline__ unsigned short bfhi(float x) {
  return (unsigned short)(__float_as_uint(x) >> 16);  // truncation split
}
__device__ __forceinline__ float bf2f(unsigned short h) {
  return __uint_as_float(((unsigned)h) << 16);
}
__device__ __forceinline__ float gelu_tanh(float x) {
  float u = 0.7978845608028654f * (x + 0.044715f * x * x * x);
  float ez = __expf(2.0f * u);
  float th = 1.0f - __fdividef(2.0f, ez + 1.0f);  // == tanh(u), correct limits
  return 0.5f * x * (1.0f + th);
}
__device__ __forceinline__ float sigmoidf_(float x) {
  return __fdividef(1.0f, 1.0f + __expf(-x));
}

// ---------------- K0: dispatch + bf16 weight planes (grid E x 2) ----------------
__global__ __launch_bounds__(256) void k_setup(
    const float* __restrict__ fp, const float* __restrict__ qw,
    const float* __restrict__ kw, const float* __restrict__ penta,
    const float* __restrict__ temp, const float* __restrict__ vw,
    int* __restrict__ idx, int* __restrict__ counts,
    unsigned short* __restrict__ qkdT_h, unsigned short* __restrict__ qkdT_l,
    unsigned short* __restrict__ vwT_h, unsigned short* __restrict__ vwT_l) {
  int e = blockIdx.x, t = threadIdx.x;
  __shared__ float s_tr[DM * 65];  // transpose staging (pad 65, conflict-free)
  if (blockIdx.y == 1) {
    // vwT: [e][d(128)][s(64)] hi/lo; both global sides coalesced via LDS
    const float* vwe = vw + (size_t)e * S * DM;
    for (int u = t; u < S * DM; u += 256) {
      int s = u >> 7, d = u & 127;           // coalesced read (u = s*128+d)
      s_tr[d * 65 + s] = vwe[u];
    }
    __syncthreads();
    for (int u = t; u < S * DM; u += 256) {  // u = d*64+s -> coalesced write
      int d = u >> 6, s = u & 63;
      float f = s_tr[d * 65 + s];
      unsigned short h = bfhi(f), l = bfhi(f - bf2f(h));
      vwT_h[(size_t)e * 8192 + u] = h;
      vwT_l[(size_t)e * 8192 + u] = l;
    }
    return;
  }
  // ---- dispatch ----
  {
    float lo = (float)e * 0.0625f, hi = (float)(e + 1) * 0.0625f;
    bool last = (e == E - 1);
    int p0 = t * 8;
    int m[8]; int ls = 0;
    #pragma unroll
    for (int k = 0; k < 8; ++k) {
      float f = fp[p0 + k];
      bool mm = (f >= lo) && (last ? (f <= hi) : (f < hi));
      m[k] = mm ? 1 : 0;
      ls += m[k];
    }
    __shared__ int sc[256];
    sc[t] = ls;
    __syncthreads();
    for (int o = 1; o < 256; o <<= 1) {
      int v = (t >= o) ? sc[t - o] : 0;
      __syncthreads();
      sc[t] += v;
      __syncthreads();
    }
    int incl = sc[t];
    int M = sc[255];
    int r = incl - ls;
    #pragma unroll
    for (int k = 0; k < 8; ++k) {
      if (m[k]) {
        if (r < C) idx[e * C + r] = p0 + k;
        r++;
      }
    }
    if (t == 0) counts[e] = (M < C) ? M : C;
  }
  __syncthreads();
  // ---- qkdT (folded penta-norm + 1/T), [e][c(16)][s(64)] hi/lo ----
  __shared__ float s_rn[5];
  if (t < 5) {
    const float* pv = penta + (e * 5 + t) * DM;
    float ss = 0.f;
    for (int d = 0; d < DM; ++d) ss += pv[d] * pv[d];
    s_rn[t] = 1.0f / sqrtf(ss);
  }
  __syncthreads();
  float invT = 1.0f / temp[0];
  int s = t & 63, cg = t >> 6;
  for (int c = cg; c < 10; c += 4) {
    int v = c % 5;
    bool isq = (c < 5);
    const float* wrow = (isq ? qw : kw) + ((size_t)e * S + s) * DM;
    const float* pv = penta + (e * 5 + v) * DM;
    float acc = 0.f;
    #pragma unroll
    for (int d4 = 0; d4 < DM / 4; ++d4) {
      float4 a = ((const float4*)wrow)[d4];
      float4 p = ((const float4*)pv)[d4];
      acc += a.x * p.x + a.y * p.y + a.z * p.z + a.w * p.w;
    }
    float val = acc * s_rn[v] * (isq ? invT : 1.0f);
    unsigned short h = bfhi(val), l = bfhi(val - bf2f(h));
    qkdT_h[(e * 16 + c) * 64 + s] = h;
    qkdT_l[(e * 16 + c) * 64 + s] = l;
  }
  for (int c = 10 + cg; c < 16; c += 4) {  // zero-pad c=10..15
    qkdT_h[(e * 16 + c) * 64 + s] = 0;
    qkdT_l[(e * 16 + c) * 64 + s] = 0;
  }
}

// ---------------- K1: out-zero + gate + Qa/Ka (MFMA) + Vt slabs, 512 thr ----------------
// 3-barrier structure: stage -> {convert(unscaled) || gate} -> MFMA(scale outputs) -> store
__global__ __launch_bounds__(512, 8) void k_p1(
    const float* __restrict__ tokens, const float* __restrict__ alpha,
    const float* __restrict__ gw1, const float* __restrict__ gb1,
    const float* __restrict__ gw2, const float* __restrict__ gb2,
    const unsigned short* __restrict__ qkdT_h, const unsigned short* __restrict__ qkdT_l,
    const unsigned short* __restrict__ vwT_h, const unsigned short* __restrict__ vwT_l,
    const int* __restrict__ idx, const int* __restrict__ counts,
    float* __restrict__ Qa, float* __restrict__ Ka,
    unsigned short* __restrict__ Vt_h, unsigned short* __restrict__ Vt_l,
    float* __restrict__ kmx, float* __restrict__ kmn,
    float* __restrict__ out) {
  int e = blockIdx.x, b = blockIdx.y, rq = blockIdx.z;
  int t = threadIdx.x;

  // zero my disjoint 4KB slice of out (replaces memset node); must run before exit
  {
    int blk = (e * B + b) * NCH + rq;  // 0..2047; 2048*1024 = B*P*DM exactly
    if (t < 256) {
      float4 z4 = {0.f, 0.f, 0.f, 0.f};
      ((float4*)out)[(size_t)blk * 256 + t] = z4;
    }
  }

  int Me = counts[e];
  int r0 = rq * RQ;
  if (r0 >= Me) {
    if (t < 5) {
      kmx[((e * 5 + t) * B + b) * NCH + rq] = -FLT_MAX;
      kmn[((e * 5 + t) * B + b) * NCH + rq] = FLT_MAX;
    }
    return;
  }

  __shared__ __align__(16) float s_f[RQ * SFT];              // 4.3 KB, f4-aligned rows
  __shared__ __align__(16) unsigned short s_fh[RQ * 72];
  __shared__ __align__(16) unsigned short s_fl[RQ * 72];
  __shared__ __align__(16) float s_gw1[S * H];
  __shared__ float s_scl[RQ];
  __shared__ float s_kx[5 * RQ], s_kn[5 * RQ];
  __shared__ __align__(16) unsigned short s_vth[DM * 16];  // [d][row]
  __shared__ __align__(16) unsigned short s_vtl[DM * 16];

  // stage: t<256 feats (16 rows x 16 f4); t>=256 gw1 (256 f4) -- all 512 busy
  if (t < 256) {
    int row = t >> 4, q4 = t & 15;
    int ii = r0 + row;
    int pos = (ii < Me) ? idx[e * C + ii] : idx[e * C];
    const float* trow = tokens + ((size_t)b * P + pos) * DFULL + e * S;
    *(float4*)(s_f + row * SFT + q4 * 4) = ((const float4*)trow)[q4];
  } else {
    int u = t - 256;
    ((float4*)s_gw1)[u] = ((const float4*)(gw1 + (size_t)e * S * H))[u];
  }
  __syncthreads();

  if (t < 256) {
    // convert UNSCALED feats to split-bf16 (scale commutes through the matmul)
    int row = t >> 4, s0 = (t & 15) * 4;
    float4 f4 = *(const float4*)(s_f + row * SFT + s0);
    float fv[4] = {f4.x, f4.y, f4.z, f4.w};
    short4v h4, l4;
    #pragma unroll
    for (int k = 0; k < 4; ++k) {
      unsigned short h = bfhi(fv[k]), l = bfhi(fv[k] - bf2f(h));
      h4[k] = (short)h;
      l4[k] = (short)l;
    }
    *(short4v*)(s_fh + row * 72 + s0) = h4;
    *(short4v*)(s_fl + row * 72 + s0) = l4;
  } else {
    // gate: one (row, j) per thread (16x16=256), direct 64-FMA, shuffle-reduce
    int u = t - 256;
    int row = u >> 4, j = u & 15;
    float hj = gb1[e * H + j];
    #pragma unroll
    for (int s4 = 0; s4 < 16; ++s4) {
      float4 f4 = *(const float4*)(s_f + row * SFT + s4 * 4);
      hj = fmaf(f4.x, s_gw1[(s4 * 4 + 0) * H + j], hj);
      hj = fmaf(f4.y, s_gw1[(s4 * 4 + 1) * H + j], hj);
      hj = fmaf(f4.z, s_gw1[(s4 * 4 + 2) * H + j], hj);
      hj = fmaf(f4.w, s_gw1[(s4 * 4 + 3) * H + j], hj);
    }
    float gz = gelu_tanh(hj) * gw2[e * H + j];
    #pragma unroll
    for (int off = 1; off < 16; off <<= 1) gz += __shfl_xor(gz, off);
    if (j == 0) {
      float aw = sigmoidf_(alpha[e]);
      s_scl[row] = sigmoidf_(gb2[e] + gz) * aw + (1.0f - aw);
    }
  }
  __syncthreads();

  int L = t & 63, wv = t >> 6, quad = L >> 4, col = L & 15;

  // V = feats @ v_w via MFMA: one 16-d fragment per wave (8 waves = 128 d)
  // outputs scaled by per-row gate scl AFTER the matmul
  {
    const unsigned short* vTh = vwT_h + (size_t)e * 8192;
    const unsigned short* vTl = vwT_l + (size_t)e * 8192;
    f32x4 va = {0.f, 0.f, 0.f, 0.f};
    int d0 = wv * 16 + col;
    #pragma unroll
    for (int kc = 0; kc < 2; ++kc) {
      int ko = kc * 32 + quad * 8;
      short8 ah = *(const short8*)(s_fh + col * 72 + ko);
      short8 al = *(const short8*)(s_fl + col * 72 + ko);
      short8 bh = *(const short8*)(vTh + d0 * 64 + ko);
      short8 bl = *(const short8*)(vTl + d0 * 64 + ko);
      va = MFMA_BF16(ah, bh, va);
      va = MFMA_BF16(ah, bl, va);
      va = MFMA_BF16(al, bh, va);
    }
    #pragma unroll
    for (int reg = 0; reg < 4; ++reg) {
      int row = quad * 4 + reg;
      float f0 = va[reg] * s_scl[row];
      unsigned short h0 = bfhi(f0), l0 = bfhi(f0 - bf2f(h0));
      s_vth[d0 * 16 + row] = h0;
      s_vtl[d0 * 16 + row] = l0;
    }
  }

  // Qa/Ka = feats @ qkd^T via MFMA (wave 0; N=16 covers c=0..9 + pad), scaled outputs
  if (wv == 0) {
    const unsigned short* qTh = qkdT_h + e * 16 * 64;
    const unsigned short* qTl = qkdT_l + e * 16 * 64;
    f32x4 qa = {0.f, 0.f, 0.f, 0.f};
    #pragma unroll
    for (int kc = 0; kc < 2; ++kc) {
      int ko = kc * 32 + quad * 8;
      short8 ah = *(const short8*)(s_fh + col * 72 + ko);
      short8 al = *(const short8*)(s_fl + col * 72 + ko);
      short8 bh = *(const short8*)(qTh + col * 64 + ko);
      short8 bl = *(const short8*)(qTl + col * 64 + ko);
      qa = MFMA_BF16(ah, bh, qa);
      qa = MFMA_BF16(ah, bl, qa);
      qa = MFMA_BF16(al, bh, qa);
    }
    #pragma unroll
    for (int reg = 0; reg < 4; ++reg) {
      int row = quad * 4 + reg;
      int ii = r0 + row;
      float val = qa[reg] * s_scl[row];
      if (col < 5) {
        if (ii < Me) Qa[((e * 5 + col) * B + b) * C + ii] = val;
      } else if (col < 10) {
        int v = col - 5;
        if (ii < Me) Ka[((e * 5 + v) * B + b) * C + ii] = val;
        s_kx[v * RQ + row] = (ii < Me) ? val : -FLT_MAX;
        s_kn[v * RQ + row] = (ii < Me) ? val : FLT_MAX;
      }
    }
  }
  __syncthreads();
  if (t < 5) {
    float mx = -FLT_MAX, mn = FLT_MAX;
    for (int r = 0; r < RQ; ++r) {
      mx = fmaxf(mx, s_kx[t * RQ + r]);
      mn = fminf(mn, s_kn[t * RQ + r]);
    }
    kmx[((e * 5 + t) * B + b) * NCH + rq] = mx;
    kmn[((e * 5 + t) * B + b) * NCH + rq] = mn;
  }
  // Vt slab store: [e][b][js(8j)][d(128)][8] -- both sides coalesced
  if (t < 256) {
    size_t base = (size_t)(e * B + b) * (DM * C);
    int jsl = t >> 7, d = t & 127;
    size_t dst = base + ((size_t)(rq * 2 + jsl) * DM + d) * 8;
    int src = d * 16 + jsl * 8;
    *(short8*)(Vt_h + dst) = *(const short8*)(s_vth + src);
    *(short8*)(Vt_l + dst) = *(const short8*)(s_vtl + src);
  }
}

// ---------------- K2: fused l-pass + w + MFMA vs slab Vt; RQ2=16 ----------------
// DOUBLE-BUFFERED s_w: phase B(n) overlaps phase A(n+1) (MFMA pipe || VALU exp pipe);
// barriers in neighbor loop 6 -> 3; Vt fragments preloaded with full-phase distance.
__global__ __launch_bounds__(512, 4) void k_p2v(
    const float* __restrict__ Qa, const float* __restrict__ Ka,
    const unsigned short* __restrict__ Vt_h, const unsigned short* __restrict__ Vt_l,
    const float* __restrict__ kmx, const float* __restrict__ kmn,
    const int* __restrict__ idx, const int* __restrict__ counts,
    const float* __restrict__ fusw, float* __restrict__ out, RoutesArg R) {
  int e = blockIdx.x, b = blockIdx.y, rq = blockIdx.z;
  int t = threadIdx.x;
  int Me = counts[e];
  int r0 = rq * RQ2;
  if (r0 >= Me) return;

  __shared__ __align__(16) float s_ka[3 * 5 * C];                   // 15 KB, staged once
  __shared__ __align__(16) unsigned short s_wh[2 * RQ2 * WST];      // 17 KB (2 planes)
  __shared__ __align__(16) unsigned short s_wl[2 * RQ2 * WST];      // 17 KB
  __shared__ float s_l[5 * RQ2];
  __shared__ float s_KX[5], s_KN[5];
  float* s_lp = (float*)s_wh;  // overlay on plane 0: 640 floats, dead before A0

  int nbs[3] = {R.nb[e][0], R.nb[e][1], R.nb[e][2]};
  int Mns[3] = {counts[nbs[0]], counts[nbs[1]], counts[nbs[2]]};
  int row = t & 15, jq = t >> 4;  // jq 0..31
  int ii = r0 + row;
  int L = t & 63, wv = t >> 6, quad = L >> 4, col = L & 15;

  // early independent loads: Qa (overlaps Ka staging) + fusw
  float qv[5];
  #pragma unroll
  for (int v = 0; v < 5; ++v)
    qv[v] = Qa[(((size_t)e * 5 + v) * B + b) * C + ii];
  float fw[5];
  #pragma unroll
  for (int v = 0; v < 5; ++v) fw[v] = fusw[v];

  // stage all 3 neighbors' Ka (960 float4) -- single staging for both passes
  for (int u = t; u < 960; u += 512) {
    int n = (u >= 640) ? 2 : ((u >= 320) ? 1 : 0);
    int r2 = u - n * 320;
    int v = r2 >> 6, off = r2 & 63;
    ((float4*)s_ka)[n * 320 + (v << 6) + off] =
        ((const float4*)(Ka + (((size_t)nbs[n] * 5 + v) * B + b) * C))[off];
  }
  // wave-parallel kmx/kmn reduce: wave wv<5 handles direction v=wv, 48 values
  if (wv < 5) {
    float KX = -FLT_MAX, KN = FLT_MAX;
    if (L < 48) {
      int n = L >> 4, k = L & 15;
      int base = ((nbs[n] * 5 + wv) * B + b) * NCH + k;
      KX = kmx[base];
      KN = kmn[base];
    }
    #pragma unroll
    for (int off = 32; off; off >>= 1) {
      KX = fmaxf(KX, __shfl_xor(KX, off));
      KN = fminf(KN, __shfl_xor(KN, off));
    }
    if (L == 0) { s_KX[wv] = KX; s_KN[wv] = KN; }
  }
  __syncthreads();

  // per-row q2/m2 (exact row max bound of scores, log2e-folded)
  float q2[5], m2[5];
  #pragma unroll
  for (int v = 0; v < 5; ++v) {
    q2[v] = qv[v] * LOG2E;
    m2[v] = ((qv[v] > 0.f) ? qv[v] * s_KX[v] : qv[v] * s_KN[v]) * LOG2E;
  }

  // l-pass over resident ka, no barriers, raw v_exp (32-way j split)
  float lp[5] = {0.f, 0.f, 0.f, 0.f, 0.f};
  for (int n = 0; n < 3; ++n) {
    const float* ka_n = s_ka + n * 1280;
    int Mn = Mns[n];
    for (int j = jq; j < Mn; j += 32) {
      #pragma unroll
      for (int v = 0; v < 5; ++v)
        lp[v] += EXP2(fmaf(q2[v], ka_n[v * C + j], -m2[v]));
    }
  }
  // combine the 4 jq-subgroups within the wave, then 8-wave final via LDS
  #pragma unroll
  for (int v = 0; v < 5; ++v) {
    lp[v] += __shfl_xor(lp[v], 16);
    lp[v] += __shfl_xor(lp[v], 32);
  }
  if (L < 16) {
    #pragma unroll
    for (int v = 0; v < 5; ++v) s_lp[(wv * 5 + v) * RQ2 + L] = lp[v];
  }
  __syncthreads();
  if (t < 80) {
    int v = t >> 4, rw = t & 15;
    float l = 0.f;
    #pragma unroll
    for (int w = 0; w < 8; ++w) l += s_lp[(w * 5 + v) * RQ2 + rw];
    s_l[v * RQ2 + rw] = l;
  }
  __syncthreads();  // s_lp (plane 0) fully consumed; A0 may overwrite

  // c2 = log2(wdir_v / l) - m2  (fold cl into exp2 arg)
  float fmx = fw[0];
  #pragma unroll
  for (int v = 1; v < 5; ++v) fmx = fmaxf(fmx, fw[v]);
  float fsum = 0.f;
  #pragma unroll
  for (int v = 0; v < 5; ++v) { fw[v] = __expf(fw[v] - fmx); fsum += fw[v]; }
  float rfs = __fdividef(1.0f, fsum);
  float c2[5];
  #pragma unroll
  for (int v = 0; v < 5; ++v) {
    float cl = __fdividef(fw[v] * rfs, s_l[v * RQ2 + row]);
    c2[v] = __log2f(cl) - m2[v];
  }

  int d0 = wv * 16 + col;  // one 16-d fragment per wave
  f32x4 acc = {0.f, 0.f, 0.f, 0.f};

  // two register fragment sets (A/B), statically named (no runtime indexing)
  short8 fAh0 = {}, fAl0 = {}, fAh1 = {}, fAl1 = {};
  short8 fAh2 = {}, fAl2 = {}, fAh3 = {}, fAl3 = {};
  short8 fBh0 = {}, fBl0 = {}, fBh1 = {}, fBl1 = {};
  short8 fBh2 = {}, fBl2 = {}, fBh3 = {}, fBl3 = {};

#define PRELOAD(N, H0, L0, H1, L1, H2, L2, H3, L3)                            \
  {                                                                           \
    int ne_ = nbs[N];                                                         \
    int kcN_ = (Mns[N] + 31) >> 5;                                            \
    const unsigned short* vbh_ = Vt_h + (size_t)(ne_ * B + b) * (DM * C);     \
    const unsigned short* vbl_ = Vt_l + (size_t)(ne_ * B + b) * (DM * C);     \
    size_t sb_ = ((size_t)quad * DM + d0) * 8;                                \
    H0 = *(const short8*)(vbh_ + sb_);                                        \
    L0 = *(const short8*)(vbl_ + sb_);                                        \
    if (kcN_ > 1) {                                                           \
      sb_ = ((size_t)(4 + quad) * DM + d0) * 8;                               \
      H1 = *(const short8*)(vbh_ + sb_);                                      \
      L1 = *(const short8*)(vbl_ + sb_);                                      \
    }                                                                         \
    if (kcN_ > 2) {                                                           \
      sb_ = ((size_t)(8 + quad) * DM + d0) * 8;                               \
      H2 = *(const short8*)(vbh_ + sb_);                                      \
      L2 = *(const short8*)(vbl_ + sb_);                                      \
    }                                                                         \
    if (kcN_ > 3) {                                                           \
      sb_ = ((size_t)(12 + quad) * DM + d0) * 8;                              \
      H3 = *(const short8*)(vbh_ + sb_);                                      \
      L3 = *(const short8*)(vbl_ + sb_);                                      \
    }                                                                         \
  }

#define PHASE_A(N, PL)                                                        \
  {                                                                           \
    int Mn_ = Mns[N];                                                         \
    const float* ka_ = s_ka + (N) * 1280;                                     \
    int jlim_ = ((Mn_ + 31) >> 5) * 32;                                       \
    for (int j0 = jq * 4; j0 < jlim_; j0 += 128) {                            \
      short4v h4, l4;                                                         \
      _Pragma("unroll")                                                       \
      for (int k2 = 0; k2 < 4; ++k2) {                                        \
        int jj = j0 + k2;                                                     \
        float ww = 0.f;                                                       \
        if (jj < Mn_) {                                                       \
          _Pragma("unroll")                                                   \
          for (int v = 0; v < 5; ++v)                                         \
            ww += EXP2(fmaf(q2[v], ka_[v * C + jj], c2[v]));                  \
        }                                                                     \
        unsigned short h_ = bfhi(ww), l_ = bfhi(ww - bf2f(h_));               \
        h4[k2] = (short)h_;                                                   \
        l4[k2] = (short)l_;                                                   \
      }                                                                       \
      *(short4v*)(s_wh + (PL) * (RQ2 * WST) + row * WST + j0) = h4;           \
      *(short4v*)(s_wl + (PL) * (RQ2 * WST) + row * WST + j0) = l4;           \
    }                                                                         \
  }

#define PHASE_B(N, PL, H0, L0, H1, L1, H2, L2, H3, L3)                        \
  {                                                                           \
    int kcN_ = (Mns[N] + 31) >> 5;                                            \
    const unsigned short* swh_ = s_wh + (PL) * (RQ2 * WST);                   \
    const unsigned short* swl_ = s_wl + (PL) * (RQ2 * WST);                   \
    {                                                                         \
      short8 ah = *(const short8*)(swh_ + col * WST + quad * 8);              \
      short8 al = *(const short8*)(swl_ + col * WST + quad * 8);              \
      acc = MFMA_BF16(ah, H0, acc);                                           \
      acc = MFMA_BF16(ah, L0, acc);                                           \
      acc = MFMA_BF16(al, H0, acc);                                           \
    }                                                                         \
    if (kcN_ > 1) {                                                           \
      short8 ah = *(const short8*)(swh_ + col * WST + 32 + quad * 8);         \
      short8 al = *(const short8*)(swl_ + col * WST + 32 + quad * 8);         \
      acc = MFMA_BF16(ah, H1, acc);                                           \
      acc = MFMA_BF16(ah, L1, acc);                                           \
      acc = MFMA_BF16(al, H1, acc);                                           \
    }                                                                         \
    if (kcN_ > 2) {                                                           \
      short8 ah = *(const short8*)(swh_ + col * WST + 64 + quad * 8);         \
      short8 al = *(const short8*)(swl_ + col * WST + 64 + quad * 8);         \
      acc = MFMA_BF16(ah, H2, acc);                                           \
      acc = MFMA_BF16(ah, L2, acc);                                           \
      acc = MFMA_BF16(al, H2, acc);                                           \
    }                                                                         \
    if (kcN_ > 3) {                                                           \
      short8 ah = *(const short8*)(swh_ + col * WST + 96 + quad * 8);         \
      short8 al = *(const short8*)(swl_ + col * WST + 96 + quad * 8);         \
      acc = MFMA_BF16(ah, H3, acc);                                           \
      acc = MFMA_BF16(ah, L3, acc);                                           \
      acc = MFMA_BF16(al, H3, acc);                                           \
    }                                                                         \
    if (kcN_ > 4) {                                                           \
      int ne_ = nbs[N];                                                       \
      const unsigned short* vbh_ = Vt_h + (size_t)(ne_ * B + b) * (DM * C);   \
      const unsigned short* vbl_ = Vt_l + (size_t)(ne_ * B + b) * (DM * C);   \
      for (int kc = 4; kc < kcN_; ++kc) {                                     \
        size_t sb = ((size_t)(kc * 4 + quad) * DM + d0) * 8;                  \
        short8 bh = *(const short8*)(vbh_ + sb);                              \
        short8 bl = *(const short8*)(vbl_ + sb);                              \
        int ko = kc * 32 + quad * 8;                                          \
        short8 ah = *(const short8*)(swh_ + col * WST + ko);                  \
        short8 al = *(const short8*)(swl_ + col * WST + ko);                  \
        acc = MFMA_BF16(ah, bh, acc);                                         \
        acc = MFMA_BF16(ah, bl, acc);                                         \
        acc = MFMA_BF16(al, bh, acc);                                         \
      }                                                                       \
    }                                                                         \
  }

  // pipeline: A0 | bar | B0 || A1 | bar | B1 || A2 | bar | B2
  PRELOAD(0, fAh0, fAl0, fAh1, fAl1, fAh2, fAl2, fAh3, fAl3)
  PHASE_A(0, 0)
  __syncthreads();

  PRELOAD(1, fBh0, fBl0, fBh1, fBl1, fBh2, fBl2, fBh3, fBl3)
  __builtin_amdgcn_s_setprio(1);
  PHASE_B(0, 0, fAh0, fAl0, fAh1, fAl1, fAh2, fAl2, fAh3, fAl3)
  PHASE_A(1, 1)
  __builtin_amdgcn_s_setprio(0);
  __syncthreads();

  PRELOAD(2, fAh0, fAl0, fAh1, fAl1, fAh2, fAl2, fAh3, fAl3)
  __builtin_amdgcn_s_setprio(1);
  PHASE_B(1, 1, fBh0, fBl0, fBh1, fBl1, fBh2, fBl2, fBh3, fBl3)
  PHASE_A(2, 0)
  __builtin_amdgcn_s_setprio(0);
  __syncthreads();

  __builtin_amdgcn_s_setprio(1);
  PHASE_B(2, 0, fAh0, fAl0, fAh1, fAl1, fAh2, fAl2, fAh3, fAl3)
  __builtin_amdgcn_s_setprio(0);

#undef PRELOAD
#undef PHASE_A
#undef PHASE_B

  // store: rows quad*4+reg at col d0; disjoint across blocks
  #pragma unroll
  for (int reg = 0; reg < 4; ++reg) {
    int rr = quad * 4 + reg;
    int iw = r0 + rr;
    if (iw < Me) {
      int pos = idx[e * C + iw];
      out[((size_t)b * P + pos) * DM + d0] = acc[reg];
    }
  }
}

// ---------------- launch ----------------
extern "C" void kernel_launch(void* const* d_in, const int* in_sizes, int n_in,
                              void* d_out, int out_size, void* d_ws, size_t ws_size,
                              hipStream_t stream) {
  const float* tokens = (const float*)d_in[0];
  const float* fingerprints = (const float*)d_in[1];
  const float* alpha = (const float*)d_in[2];
  const float* gw1 = (const float*)d_in[3];
  const float* gb1 = (const float*)d_in[4];
  const float* gw2 = (const float*)d_in[5];
  const float* gb2 = (const float*)d_in[6];
  const float* qw = (const float*)d_in[7];
  const float* kw = (const float*)d_in[8];
  const float* vw = (const float*)d_in[9];
  const float* penta = (const float*)d_in[10];
  const float* fusw = (const float*)d_in[11];
  const float* temp = (const float*)d_in[12];
  float* out = (float*)d_out;

  float* ws = (float*)d_ws;
  float* Qa = ws;                                   // E*5*B*C
  float* Ka = Qa + (size_t)E * 5 * B * C;
  float* kmx = Ka + (size_t)E * 5 * B * C;          // E*5*B*NCH
  float* kmn = kmx + (size_t)E * 5 * B * NCH;
  unsigned short* qkdT_h = (unsigned short*)(kmn + (size_t)E * 5 * B * NCH);
  unsigned short* qkdT_l = qkdT_h + (size_t)E * 16 * 64;
  unsigned short* vwT_h = qkdT_l + (size_t)E * 16 * 64;
  unsigned short* vwT_l = vwT_h + (size_t)E * S * DM;
  unsigned short* Vt_h = vwT_l + (size_t)E * S * DM;       // E*B*DM*C (slabbed)
  unsigned short* Vt_l = Vt_h + (size_t)E * B * DM * C;
  int* idx = (int*)(Vt_l + (size_t)E * B * DM * C);
  int* counts = idx + (size_t)E * C;

  RoutesArg R;
  compute_routes(R.nb);

  k_setup<<<dim3(E, 2), dim3(256), 0, stream>>>(fingerprints, qw, kw, penta, temp, vw,
                                                idx, counts, qkdT_h, qkdT_l, vwT_h, vwT_l);
  k_p1<<<dim3(E, B, NCH), dim3(512), 0, stream>>>(tokens, alpha, gw1, gb1, gw2, gb2,
                                                  qkdT_h, qkdT_l, vwT_h, vwT_l,
                                                  idx, counts, Qa, Ka, Vt_h, Vt_l,
                                                  kmx, kmn, out);
  k_p2v<<<dim3(E, B, NCH2), dim3(512), 0, stream>>>(Qa, Ka, Vt_h, Vt_l, kmx, kmn,
                                                    idx, counts, fusw, out, R);
}

// Round 9
// 166.941 us; speedup vs baseline: 1.0336x; 1.0336x over previous
//
#include <hip/hip_runtime.h>
#include <cfloat>
#include <math.h>

#define E 16
#define DFULL 1024
#define DM 128
#define S 64
#define P 2048
#define B 8
#define C 256
#define W 3
#define H 16
#define RQ 16   /* rows per k_p1 block chunk */
#define NCH 16  /* row chunks per (e,b) for k_p1 / kmx planes */
#define RQ2 16  /* rows per k_p2v block chunk */
#define NCH2 16 /* row chunks per (e,b) for k_p2v */
#define LOG2E 1.4426950408889634f
#define WST 272 /* s_w stride in u16: 16B-aligned rows */
#define SFT 68  /* s_f stride in floats: 16B-aligned rows, odd dword-quad */

typedef __attribute__((ext_vector_type(8))) short short8;
typedef __attribute__((ext_vector_type(4))) short short4v;
typedef __attribute__((ext_vector_type(4))) float f32x4;
#define MFMA_BF16(a, b, c) __builtin_amdgcn_mfma_f32_16x16x32_bf16((a), (b), (c), 0, 0, 0)

#if defined(__HIP_DEVICE_COMPILE__) && __has_builtin(__builtin_amdgcn_exp2f)
#define EXP2(x) __builtin_amdgcn_exp2f(x)
#else
#define EXP2(x) exp2f(x)
#endif

struct RoutesArg { int nb[E][W]; };

// ---------------- host: replicate _expert_routes() exactly ----------------
static void compute_routes(int r[E][W]) {
  float coords[E];
  for (int i = 0; i < E; ++i) {
    double x = (double)i / (double)(E - 1);
    if (x < 1e-06) x = 1e-06;
    if (x > 1.0 - 1e-06) x = 1.0 - 1e-06;
    double val = 0.0, factor = 0.5;
    for (int k = 0; k < 8; ++k) {
      x *= 3.0;
      int d = (int)x;
      x -= (double)d;
      if (d == 2) val += factor;
      factor *= 0.5;
    }
    coords[i] = (float)val;
  }
  for (int e = 0; e < E; ++e) {
    float de[E];
    for (int i = 0; i < E; ++i) de[i] = fabsf(coords[i] - coords[e]);
    bool used[E] = {false};
    for (int w = 0; w < W; ++w) {
      int best = -1; float bd = FLT_MAX;
      for (int i = 0; i < E; ++i)
        if (!used[i] && de[i] < bd) { bd = de[i]; best = i; }  // strict < = stable
      used[best] = true;
      r[e][w] = best;
    }
  }
}

__device__ __forceinline__ unsigned short bfhi(float x) {
  return (unsigned short)(__float_as_uint(x) >> 16);  // truncation split
}
__device__ __forceinline__ float bf2f(unsigned short h) {
  return __uint_as_float(((unsigned)h) << 16);
}
__device__ __forceinline__ float gelu_tanh(float x) {
  float u = 0.7978845608028654f * (x + 0.044715f * x * x * x);
  float ez = __expf(2.0f * u);
  float th = 1.0f - __fdividef(2.0f, ez + 1.0f);  // == tanh(u), correct limits
  return 0.5f * x * (1.0f + th);
}
__device__ __forceinline__ float sigmoidf_(float x) {
  return __fdividef(1.0f, 1.0f + __expf(-x));
}

// ---------------- K0: dispatch + bf16 weight planes (grid E x 2) ----------------
__global__ __launch_bounds__(256) void k_setup(
    const float* __restrict__ fp, const float* __restrict__ qw,
    const float* __restrict__ kw, const float* __restrict__ penta,
    const float* __restrict__ temp, const float* __restrict__ vw,
    int* __restrict__ idx, int* __restrict__ counts,
    unsigned short* __restrict__ qkdT_h, unsigned short* __restrict__ qkdT_l,
    unsigned short* __restrict__ vwT_h, unsigned short* __restrict__ vwT_l) {
  int e = blockIdx.x, t = threadIdx.x;
  __shared__ float s_tr[DM * 65];  // transpose staging (pad 65, conflict-free)
  if (blockIdx.y == 1) {
    // vwT: [e][d(128)][s(64)] hi/lo; both global sides coalesced via LDS
    const float* vwe = vw + (size_t)e * S * DM;
    for (int u = t; u < S * DM; u += 256) {
      int s = u >> 7, d = u & 127;           // coalesced read (u = s*128+d)
      s_tr[d * 65 + s] = vwe[u];
    }
    __syncthreads();
    for (int u = t; u < S * DM; u += 256) {  // u = d*64+s -> coalesced write
      int d = u >> 6, s = u & 63;
      float f = s_tr[d * 65 + s];
      unsigned short h = bfhi(f), l = bfhi(f - bf2f(h));
      vwT_h[(size_t)e * 8192 + u] = h;
      vwT_l[(size_t)e * 8192 + u] = l;
    }
    return;
  }
  // ---- dispatch ----
  {
    float lo = (float)e * 0.0625f, hi = (float)(e + 1) * 0.0625f;
    bool last = (e == E - 1);
    int p0 = t * 8;
    int m[8]; int ls = 0;
    #pragma unroll
    for (int k = 0; k < 8; ++k) {
      float f = fp[p0 + k];
      bool mm = (f >= lo) && (last ? (f <= hi) : (f < hi));
      m[k] = mm ? 1 : 0;
      ls += m[k];
    }
    __shared__ int sc[256];
    sc[t] = ls;
    __syncthreads();
    for (int o = 1; o < 256; o <<= 1) {
      int v = (t >= o) ? sc[t - o] : 0;
      __syncthreads();
      sc[t] += v;
      __syncthreads();
    }
    int incl = sc[t];
    int M = sc[255];
    int r = incl - ls;
    #pragma unroll
    for (int k = 0; k < 8; ++k) {
      if (m[k]) {
        if (r < C) idx[e * C + r] = p0 + k;
        r++;
      }
    }
    if (t == 0) counts[e] = (M < C) ? M : C;
  }
  __syncthreads();
  // ---- qkdT (folded penta-norm + 1/T), [e][c(16)][s(64)] hi/lo ----
  __shared__ float s_rn[5];
  if (t < 5) {
    const float* pv = penta + (e * 5 + t) * DM;
    float ss = 0.f;
    for (int d = 0; d < DM; ++d) ss += pv[d] * pv[d];
    s_rn[t] = 1.0f / sqrtf(ss);
  }
  __syncthreads();
  float invT = 1.0f / temp[0];
  int s = t & 63, cg = t >> 6;
  for (int c = cg; c < 10; c += 4) {
    int v = c % 5;
    bool isq = (c < 5);
    const float* wrow = (isq ? qw : kw) + ((size_t)e * S + s) * DM;
    const float* pv = penta + (e * 5 + v) * DM;
    float acc = 0.f;
    #pragma unroll
    for (int d4 = 0; d4 < DM / 4; ++d4) {
      float4 a = ((const float4*)wrow)[d4];
      float4 p = ((const float4*)pv)[d4];
      acc += a.x * p.x + a.y * p.y + a.z * p.z + a.w * p.w;
    }
    float val = acc * s_rn[v] * (isq ? invT : 1.0f);
    unsigned short h = bfhi(val), l = bfhi(val - bf2f(h));
    qkdT_h[(e * 16 + c) * 64 + s] = h;
    qkdT_l[(e * 16 + c) * 64 + s] = l;
  }
  for (int c = 10 + cg; c < 16; c += 4) {  // zero-pad c=10..15
    qkdT_h[(e * 16 + c) * 64 + s] = 0;
    qkdT_l[(e * 16 + c) * 64 + s] = 0;
  }
}

// ---------------- K1: out-zero + gate + Qa/Ka (MFMA) + Vt slabs, 512 thr ----------------
// 3-barrier structure: stage -> {convert(unscaled) || gate} -> MFMA(scale outputs) -> store
__global__ __launch_bounds__(512, 8) void k_p1(
    const float* __restrict__ tokens, const float* __restrict__ alpha,
    const float* __restrict__ gw1, const float* __restrict__ gb1,
    const float* __restrict__ gw2, const float* __restrict__ gb2,
    const unsigned short* __restrict__ qkdT_h, const unsigned short* __restrict__ qkdT_l,
    const unsigned short* __restrict__ vwT_h, const unsigned short* __restrict__ vwT_l,
    const int* __restrict__ idx, const int* __restrict__ counts,
    float* __restrict__ Qa, float* __restrict__ Ka,
    unsigned short* __restrict__ Vt_h, unsigned short* __restrict__ Vt_l,
    float* __restrict__ kmx, float* __restrict__ kmn,
    float* __restrict__ out) {
  int e = blockIdx.x, b = blockIdx.y, rq = blockIdx.z;
  int t = threadIdx.x;

  // zero my disjoint 4KB slice of out (replaces memset node); must run before exit
  {
    int blk = (e * B + b) * NCH + rq;  // 0..2047; 2048*1024 = B*P*DM exactly
    if (t < 256) {
      float4 z4 = {0.f, 0.f, 0.f, 0.f};
      ((float4*)out)[(size_t)blk * 256 + t] = z4;
    }
  }

  int Me = counts[e];
  int r0 = rq * RQ;
  if (r0 >= Me) {
    if (t < 5) {
      kmx[((e * 5 + t) * B + b) * NCH + rq] = -FLT_MAX;
      kmn[((e * 5 + t) * B + b) * NCH + rq] = FLT_MAX;
    }
    return;
  }

  __shared__ __align__(16) float s_f[RQ * SFT];              // 4.3 KB, f4-aligned rows
  __shared__ __align__(16) unsigned short s_fh[RQ * 72];
  __shared__ __align__(16) unsigned short s_fl[RQ * 72];
  __shared__ __align__(16) float s_gw1[S * H];
  __shared__ float s_scl[RQ];
  __shared__ float s_kx[5 * RQ], s_kn[5 * RQ];
  __shared__ __align__(16) unsigned short s_vth[DM * 16];  // [d][row]
  __shared__ __align__(16) unsigned short s_vtl[DM * 16];

  // stage: t<256 feats (16 rows x 16 f4); t>=256 gw1 (256 f4) -- all 512 busy
  if (t < 256) {
    int row = t >> 4, q4 = t & 15;
    int ii = r0 + row;
    int pos = (ii < Me) ? idx[e * C + ii] : idx[e * C];
    const float* trow = tokens + ((size_t)b * P + pos) * DFULL + e * S;
    *(float4*)(s_f + row * SFT + q4 * 4) = ((const float4*)trow)[q4];
  } else {
    int u = t - 256;
    ((float4*)s_gw1)[u] = ((const float4*)(gw1 + (size_t)e * S * H))[u];
  }
  __syncthreads();

  if (t < 256) {
    // convert UNSCALED feats to split-bf16 (scale commutes through the matmul)
    int row = t >> 4, s0 = (t & 15) * 4;
    float4 f4 = *(const float4*)(s_f + row * SFT + s0);
    float fv[4] = {f4.x, f4.y, f4.z, f4.w};
    short4v h4, l4;
    #pragma unroll
    for (int k = 0; k < 4; ++k) {
      unsigned short h = bfhi(fv[k]), l = bfhi(fv[k] - bf2f(h));
      h4[k] = (short)h;
      l4[k] = (short)l;
    }
    *(short4v*)(s_fh + row * 72 + s0) = h4;
    *(short4v*)(s_fl + row * 72 + s0) = l4;
  } else {
    // gate: one (row, j) per thread (16x16=256), direct 64-FMA, shuffle-reduce
    int u = t - 256;
    int row = u >> 4, j = u & 15;
    float hj = gb1[e * H + j];
    #pragma unroll
    for (int s4 = 0; s4 < 16; ++s4) {
      float4 f4 = *(const float4*)(s_f + row * SFT + s4 * 4);
      hj = fmaf(f4.x, s_gw1[(s4 * 4 + 0) * H + j], hj);
      hj = fmaf(f4.y, s_gw1[(s4 * 4 + 1) * H + j], hj);
      hj = fmaf(f4.z, s_gw1[(s4 * 4 + 2) * H + j], hj);
      hj = fmaf(f4.w, s_gw1[(s4 * 4 + 3) * H + j], hj);
    }
    float gz = gelu_tanh(hj) * gw2[e * H + j];
    #pragma unroll
    for (int off = 1; off < 16; off <<= 1) gz += __shfl_xor(gz, off);
    if (j == 0) {
      float aw = sigmoidf_(alpha[e]);
      s_scl[row] = sigmoidf_(gb2[e] + gz) * aw + (1.0f - aw);
    }
  }
  __syncthreads();

  int L = t & 63, wv = t >> 6, quad = L >> 4, col = L & 15;

  // V = feats @ v_w via MFMA: one 16-d fragment per wave (8 waves = 128 d)
  // outputs scaled by per-row gate scl AFTER the matmul
  {
    const unsigned short* vTh = vwT_h + (size_t)e * 8192;
    const unsigned short* vTl = vwT_l + (size_t)e * 8192;
    f32x4 va = {0.f, 0.f, 0.f, 0.f};
    int d0 = wv * 16 + col;
    #pragma unroll
    for (int kc = 0; kc < 2; ++kc) {
      int ko = kc * 32 + quad * 8;
      short8 ah = *(const short8*)(s_fh + col * 72 + ko);
      short8 al = *(const short8*)(s_fl + col * 72 + ko);
      short8 bh = *(const short8*)(vTh + d0 * 64 + ko);
      short8 bl = *(const short8*)(vTl + d0 * 64 + ko);
      va = MFMA_BF16(ah, bh, va);
      va = MFMA_BF16(ah, bl, va);
      va = MFMA_BF16(al, bh, va);
    }
    #pragma unroll
    for (int reg = 0; reg < 4; ++reg) {
      int row = quad * 4 + reg;
      float f0 = va[reg] * s_scl[row];
      unsigned short h0 = bfhi(f0), l0 = bfhi(f0 - bf2f(h0));
      s_vth[d0 * 16 + row] = h0;
      s_vtl[d0 * 16 + row] = l0;
    }
  }

  // Qa/Ka = feats @ qkd^T via MFMA (wave 0; N=16 covers c=0..9 + pad), scaled outputs
  if (wv == 0) {
    const unsigned short* qTh = qkdT_h + e * 16 * 64;
    const unsigned short* qTl = qkdT_l + e * 16 * 64;
    f32x4 qa = {0.f, 0.f, 0.f, 0.f};
    #pragma unroll
    for (int kc = 0; kc < 2; ++kc) {
      int ko = kc * 32 + quad * 8;
      short8 ah = *(const short8*)(s_fh + col * 72 + ko);
      short8 al = *(const short8*)(s_fl + col * 72 + ko);
      short8 bh = *(const short8*)(qTh + col * 64 + ko);
      short8 bl = *(const short8*)(qTl + col * 64 + ko);
      qa = MFMA_BF16(ah, bh, qa);
      qa = MFMA_BF16(ah, bl, qa);
      qa = MFMA_BF16(al, bh, qa);
    }
    #pragma unroll
    for (int reg = 0; reg < 4; ++reg) {
      int row = quad * 4 + reg;
      int ii = r0 + row;
      float val = qa[reg] * s_scl[row];
      if (col < 5) {
        if (ii < Me) Qa[((e * 5 + col) * B + b) * C + ii] = val;
      } else if (col < 10) {
        int v = col - 5;
        if (ii < Me) Ka[((e * 5 + v) * B + b) * C + ii] = val;
        s_kx[v * RQ + row] = (ii < Me) ? val : -FLT_MAX;
        s_kn[v * RQ + row] = (ii < Me) ? val : FLT_MAX;
      }
    }
  }
  __syncthreads();
  if (t < 5) {
    float mx = -FLT_MAX, mn = FLT_MAX;
    for (int r = 0; r < RQ; ++r) {
      mx = fmaxf(mx, s_kx[t * RQ + r]);
      mn = fminf(mn, s_kn[t * RQ + r]);
    }
    kmx[((e * 5 + t) * B + b) * NCH + rq] = mx;
    kmn[((e * 5 + t) * B + b) * NCH + rq] = mn;
  }
  // Vt slab store: [e][b][js(8j)][d(128)][8] -- both sides coalesced
  if (t < 256) {
    size_t base = (size_t)(e * B + b) * (DM * C);
    int jsl = t >> 7, d = t & 127;
    size_t dst = base + ((size_t)(rq * 2 + jsl) * DM + d) * 8;
    int src = d * 16 + jsl * 8;
    *(short8*)(Vt_h + dst) = *(const short8*)(s_vth + src);
    *(short8*)(Vt_l + dst) = *(const short8*)(s_vtl + src);
  }
}

// ---------------- K2: fused l-pass + w + MFMA vs slab Vt; RQ2=16 ----------------
// phase-B Vt fragments fully PRELOADED before phase A (no dependency on s_w) ->
// L2 latency hidden under the exp stream; needs VGPR headroom -> launch_bounds (512,4)
__global__ __launch_bounds__(512, 4) void k_p2v(
    const float* __restrict__ Qa, const float* __restrict__ Ka,
    const unsigned short* __restrict__ Vt_h, const unsigned short* __restrict__ Vt_l,
    const float* __restrict__ kmx, const float* __restrict__ kmn,
    const int* __restrict__ idx, const int* __restrict__ counts,
    const float* __restrict__ fusw, float* __restrict__ out, RoutesArg R) {
  int e = blockIdx.x, b = blockIdx.y, rq = blockIdx.z;
  int t = threadIdx.x;
  int Me = counts[e];
  int r0 = rq * RQ2;
  if (r0 >= Me) return;

  __shared__ __align__(16) float s_ka[3 * 5 * C];                // 15 KB, staged once
  __shared__ __align__(16) unsigned short s_wh[RQ2 * WST];       // 8.5 KB
  __shared__ __align__(16) unsigned short s_wl[RQ2 * WST];       // 8.5 KB
  __shared__ float s_l[5 * RQ2];
  __shared__ float s_KX[5], s_KN[5];
  float* s_lp = (float*)s_wh;  // overlay: 8*5*16 floats, dead before phase A

  int nbs[3] = {R.nb[e][0], R.nb[e][1], R.nb[e][2]};
  int Mns[3] = {counts[nbs[0]], counts[nbs[1]], counts[nbs[2]]};
  int row = t & 15, jq = t >> 4;  // jq 0..31
  int ii = r0 + row;
  int L = t & 63, wv = t >> 6, quad = L >> 4, col = L & 15;

  // early independent loads: Qa (overlaps Ka staging) + fusw
  float qv[5];
  #pragma unroll
  for (int v = 0; v < 5; ++v)
    qv[v] = Qa[(((size_t)e * 5 + v) * B + b) * C + ii];
  float fw[5];
  #pragma unroll
  for (int v = 0; v < 5; ++v) fw[v] = fusw[v];

  // stage all 3 neighbors' Ka (960 float4) -- single staging for both passes
  for (int u = t; u < 960; u += 512) {
    int n = (u >= 640) ? 2 : ((u >= 320) ? 1 : 0);
    int r2 = u - n * 320;
    int v = r2 >> 6, off = r2 & 63;
    ((float4*)s_ka)[n * 320 + (v << 6) + off] =
        ((const float4*)(Ka + (((size_t)nbs[n] * 5 + v) * B + b) * C))[off];
  }
  // wave-parallel kmx/kmn reduce: wave wv<5 handles direction v=wv, 48 values
  if (wv < 5) {
    float KX = -FLT_MAX, KN = FLT_MAX;
    if (L < 48) {
      int n = L >> 4, k = L & 15;
      int base = ((nbs[n] * 5 + wv) * B + b) * NCH + k;
      KX = kmx[base];
      KN = kmn[base];
    }
    #pragma unroll
    for (int off = 32; off; off >>= 1) {
      KX = fmaxf(KX, __shfl_xor(KX, off));
      KN = fminf(KN, __shfl_xor(KN, off));
    }
    if (L == 0) { s_KX[wv] = KX; s_KN[wv] = KN; }
  }
  __syncthreads();

  // per-row q2/m2 (exact row max bound of scores, log2e-folded)
  float q2[5], m2[5];
  #pragma unroll
  for (int v = 0; v < 5; ++v) {
    q2[v] = qv[v] * LOG2E;
    m2[v] = ((qv[v] > 0.f) ? qv[v] * s_KX[v] : qv[v] * s_KN[v]) * LOG2E;
  }

  // l-pass over resident ka, no barriers, raw v_exp (32-way j split)
  float lp[5] = {0.f, 0.f, 0.f, 0.f, 0.f};
  for (int n = 0; n < 3; ++n) {
    const float* ka_n = s_ka + n * 1280;
    int Mn = Mns[n];
    for (int j = jq; j < Mn; j += 32) {
      #pragma unroll
      for (int v = 0; v < 5; ++v)
        lp[v] += EXP2(fmaf(q2[v], ka_n[v * C + j], -m2[v]));
    }
  }
  // combine the 4 jq-subgroups within the wave, then 8-wave final via LDS
  #pragma unroll
  for (int v = 0; v < 5; ++v) {
    lp[v] += __shfl_xor(lp[v], 16);
    lp[v] += __shfl_xor(lp[v], 32);
  }
  if (L < 16) {
    #pragma unroll
    for (int v = 0; v < 5; ++v) s_lp[(wv * 5 + v) * RQ2 + L] = lp[v];
  }
  __syncthreads();
  if (t < 80) {
    int v = t >> 4, rw = t & 15;
    float l = 0.f;
    #pragma unroll
    for (int w = 0; w < 8; ++w) l += s_lp[(w * 5 + v) * RQ2 + rw];
    s_l[v * RQ2 + rw] = l;
  }
  __syncthreads();

  // c2 = log2(wdir_v / l) - m2  (fold cl into exp2 arg)
  float fmx = fw[0];
  #pragma unroll
  for (int v = 1; v < 5; ++v) fmx = fmaxf(fmx, fw[v]);
  float fsum = 0.f;
  #pragma unroll
  for (int v = 0; v < 5; ++v) { fw[v] = __expf(fw[v] - fmx); fsum += fw[v]; }
  float rfs = __fdividef(1.0f, fsum);
  float c2[5];
  #pragma unroll
  for (int v = 0; v < 5; ++v) {
    float cl = __fdividef(fw[v] * rfs, s_l[v * RQ2 + row]);
    c2[v] = __log2f(cl) - m2[v];
  }

  int d0 = wv * 16 + col;  // one 16-d fragment per wave
  f32x4 acc = {0.f, 0.f, 0.f, 0.f};

  for (int n = 0; n < 3; ++n) {
    int ne = nbs[n], Mn = Mns[n];
    int kcN = (Mn + 31) >> 5;
    const float* ka_n = s_ka + n * 1280;
    __syncthreads();  // prior phase-B s_w reads done (also covers s_lp overlay)
    // PRELOAD all (up to 4) kc fragment pairs NOW: load-use distance = entire phase A
    const unsigned short* vbh = Vt_h + (size_t)(ne * B + b) * (DM * C);
    const unsigned short* vbl = Vt_l + (size_t)(ne * B + b) * (DM * C);
    short8 pbh0 = {}, pbl0 = {}, pbh1 = {}, pbl1 = {};
    short8 pbh2 = {}, pbl2 = {}, pbh3 = {}, pbl3 = {};
    {
      size_t sb = ((size_t)quad * DM + d0) * 8;
      pbh0 = *(const short8*)(vbh + sb);
      pbl0 = *(const short8*)(vbl + sb);
      if (kcN > 1) {
        sb = ((size_t)(4 + quad) * DM + d0) * 8;
        pbh1 = *(const short8*)(vbh + sb);
        pbl1 = *(const short8*)(vbl + sb);
      }
      if (kcN > 2) {
        sb = ((size_t)(8 + quad) * DM + d0) * 8;
        pbh2 = *(const short8*)(vbh + sb);
        pbl2 = *(const short8*)(vbl + sb);
      }
      if (kcN > 3) {
        sb = ((size_t)(12 + quad) * DM + d0) * 8;
        pbh3 = *(const short8*)(vbh + sb);
        pbl3 = *(const short8*)(vbl + sb);
      }
    }
    // phase A: combined weights, 4 j per thread (32 jq groups x 4 = 128 j), b64 writes
    int jlim = kcN * 32;
    for (int j0 = jq * 4; j0 < jlim; j0 += 128) {
      short4v h4, l4;
      #pragma unroll
      for (int k2 = 0; k2 < 4; ++k2) {
        int jj = j0 + k2;
        float ww = 0.f;
        if (jj < Mn) {
          #pragma unroll
          for (int v = 0; v < 5; ++v)
            ww += EXP2(fmaf(q2[v], ka_n[v * C + jj], c2[v]));
        }
        unsigned short h = bfhi(ww), l = bfhi(ww - bf2f(h));
        h4[k2] = (short)h;
        l4[k2] = (short)l;
      }
      *(short4v*)(s_wh + row * WST + j0) = h4;
      *(short4v*)(s_wl + row * WST + j0) = l4;
    }
    __syncthreads();
    // phase B: MFMA from LDS weights x preloaded register fragments (zero load waits)
    __builtin_amdgcn_s_setprio(1);
#define K2V_STEP(KC, PH, PL)                                      \
    if (kcN > KC) {                                               \
      int ko = KC * 32 + quad * 8;                                \
      short8 ah = *(const short8*)(s_wh + col * WST + ko);        \
      short8 al = *(const short8*)(s_wl + col * WST + ko);        \
      acc = MFMA_BF16(ah, PH, acc);                               \
      acc = MFMA_BF16(ah, PL, acc);                               \
      acc = MFMA_BF16(al, PH, acc);                               \
    }
    K2V_STEP(0, pbh0, pbl0)
    K2V_STEP(1, pbh1, pbl1)
    K2V_STEP(2, pbh2, pbl2)
    K2V_STEP(3, pbh3, pbl3)
#undef K2V_STEP
    // tail (kcN>4, rare): in-loop loads with distance-1 prefetch
    for (int kc = 4; kc < kcN; ++kc) {
      size_t sb = ((size_t)(kc * 4 + quad) * DM + d0) * 8;
      short8 bh = *(const short8*)(vbh + sb);
      short8 bl = *(const short8*)(vbl + sb);
      int ko = kc * 32 + quad * 8;
      short8 ah = *(const short8*)(s_wh + col * WST + ko);
      short8 al = *(const short8*)(s_wl + col * WST + ko);
      acc = MFMA_BF16(ah, bh, acc);
      acc = MFMA_BF16(ah, bl, acc);
      acc = MFMA_BF16(al, bh, acc);
    }
    __builtin_amdgcn_s_setprio(0);
  }

  // store: rows quad*4+reg at col d0; disjoint across blocks
  #pragma unroll
  for (int reg = 0; reg < 4; ++reg) {
    int rr = quad * 4 + reg;
    int iw = r0 + rr;
    if (iw < Me) {
      int pos = idx[e * C + iw];
      out[((size_t)b * P + pos) * DM + d0] = acc[reg];
    }
  }
}

// ---------------- launch ----------------
extern "C" void kernel_launch(void* const* d_in, const int* in_sizes, int n_in,
                              void* d_out, int out_size, void* d_ws, size_t ws_size,
                              hipStream_t stream) {
  const float* tokens = (const float*)d_in[0];
  const float* fingerprints = (const float*)d_in[1];
  const float* alpha = (const float*)d_in[2];
  const float* gw1 = (const float*)d_in[3];
  const float* gb1 = (const float*)d_in[4];
  const float* gw2 = (const float*)d_in[5];
  const float* gb2 = (const float*)d_in[6];
  const float* qw = (const float*)d_in[7];
  const float* kw = (const float*)d_in[8];
  const float* vw = (const float*)d_in[9];
  const float* penta = (const float*)d_in[10];
  const float* fusw = (const float*)d_in[11];
  const float* temp = (const float*)d_in[12];
  float* out = (float*)d_out;

  float* ws = (float*)d_ws;
  float* Qa = ws;                                   // E*5*B*C
  float* Ka = Qa + (size_t)E * 5 * B * C;
  float* kmx = Ka + (size_t)E * 5 * B * C;          // E*5*B*NCH
  float* kmn = kmx + (size_t)E * 5 * B * NCH;
  unsigned short* qkdT_h = (unsigned short*)(kmn + (size_t)E * 5 * B * NCH);
  unsigned short* qkdT_l = qkdT_h + (size_t)E * 16 * 64;
  unsigned short* vwT_h = qkdT_l + (size_t)E * 16 * 64;
  unsigned short* vwT_l = vwT_h + (size_t)E * S * DM;
  unsigned short* Vt_h = vwT_l + (size_t)E * S * DM;       // E*B*DM*C (slabbed)
  unsigned short* Vt_l = Vt_h + (size_t)E * B * DM * C;
  int* idx = (int*)(Vt_l + (size_t)E * B * DM * C);
  int* counts = idx + (size_t)E * C;

  RoutesArg R;
  compute_routes(R.nb);

  k_setup<<<dim3(E, 2), dim3(256), 0, stream>>>(fingerprints, qw, kw, penta, temp, vw,
                                                idx, counts, qkdT_h, qkdT_l, vwT_h, vwT_l);
  k_p1<<<dim3(E, B, NCH), dim3(512), 0, stream>>>(tokens, alpha, gw1, gb1, gw2, gb2,
                                                  qkdT_h, qkdT_l, vwT_h, vwT_l,
                                                  idx, counts, Qa, Ka, Vt_h, Vt_l,
                                                  kmx, kmn, out);
  k_p2v<<<dim3(E, B, NCH2), dim3(512), 0, stream>>>(Qa, Ka, Vt_h, Vt_l, kmx, kmn,
                                                    idx, counts, fusw, out, R);
}